// Round 1
// baseline (11783.426 us; speedup 1.0000x reference)
//
#include <hip/hip_runtime.h>
#include <cmath>

// Problem constants (setup_inputs): B=64, S=1024, I=1024, H=1024, fp32.
constexpr int B = 64, S = 1024, I = 1024, H = 1024;
constexpr int KSPLIT = 16;            // scan K-split: 16 gtiles x 16 ksplits = 256 blocks

// ---------------------------------------------------------------------------
// Phase 1: wx[m,n] = sum_k x[m,k] * Wih_w[n,k] + Wih_b[n]
// A: [M=65536, K=1024] row-major; W: [N=1024, K=1024] row-major (NT GEMM).
// 64x64 tile, BK=16, 256 threads, 4x4 micro-tile. fp32 VALU.
// ---------------------------------------------------------------------------
__global__ __launch_bounds__(256) void gemm_nt(
    const float* __restrict__ A, const float* __restrict__ W,
    const float* __restrict__ bias, float* __restrict__ C) {
  __shared__ float As[16][68];   // [k][m], +4 pad keeps float4 alignment
  __shared__ float Bs[16][68];   // [k][n]
  const int tid = threadIdx.x;
  const int m0 = blockIdx.y * 64;
  const int n0 = blockIdx.x * 64;
  const int tx = tid & 15;        // n-thread
  const int ty = tid >> 4;        // m-thread
  const int lr = tid >> 2;        // 0..63 staging row
  const int lc = (tid & 3) * 4;   // 0,4,8,12 staging col (k)

  const float* Ap = A + (size_t)(m0 + lr) * I + lc;
  const float* Wp = W + (size_t)(n0 + lr) * I + lc;

  float acc[4][4] = {};
  for (int k0 = 0; k0 < I; k0 += 16) {
    float4 av = *(const float4*)(Ap + k0);
    float4 wv = *(const float4*)(Wp + k0);
    As[lc + 0][lr] = av.x; As[lc + 1][lr] = av.y;
    As[lc + 2][lr] = av.z; As[lc + 3][lr] = av.w;
    Bs[lc + 0][lr] = wv.x; Bs[lc + 1][lr] = wv.y;
    Bs[lc + 2][lr] = wv.z; Bs[lc + 3][lr] = wv.w;
    __syncthreads();
#pragma unroll
    for (int kk = 0; kk < 16; ++kk) {
      float4 a = *(const float4*)&As[kk][ty * 4];
      float4 b = *(const float4*)&Bs[kk][tx * 4];
      float ar[4] = {a.x, a.y, a.z, a.w};
      float br[4] = {b.x, b.y, b.z, b.w};
#pragma unroll
      for (int i = 0; i < 4; ++i)
#pragma unroll
        for (int j = 0; j < 4; ++j) acc[i][j] += ar[i] * br[j];
    }
    __syncthreads();
  }
  float bj[4];
#pragma unroll
  for (int j = 0; j < 4; ++j) bj[j] = bias[n0 + tx * 4 + j];
#pragma unroll
  for (int i = 0; i < 4; ++i) {
    int m = m0 + ty * 4 + i;
    float4 o = make_float4(acc[i][0] + bj[0], acc[i][1] + bj[1],
                           acc[i][2] + bj[2], acc[i][3] + bj[3]);
    *(float4*)&C[(size_t)m * H + n0 + tx * 4] = o;
  }
}

// ---------------------------------------------------------------------------
// Scan step GEMM: partial[kb][b][g] = sum_{k in kb-chunk} hprev[b,k] * Whh[g,k]
// Grid: (H/64 gtiles, KSPLIT). Block: 64b x 64g tile over 64-deep K chunk.
// hprev has row stride `hstride` (H for t=0 initial h, S*H for y slices).
// ---------------------------------------------------------------------------
__global__ __launch_bounds__(256) void rnn_step_gemm(
    const float* __restrict__ hprev, long hstride,
    const float* __restrict__ W, float* __restrict__ partial) {
  __shared__ float Ws[64][68];   // [k][g]
  __shared__ float Hs[64][68];   // [k][b]
  const int tid = threadIdx.x;
  const int g0 = blockIdx.x * 64;
  const int k0 = blockIdx.y * 64;
  const int tx = tid & 15;       // g-thread
  const int ty = tid >> 4;       // b-thread

  {
    const int r = tid >> 4;          // 0..15
    const int c = (tid & 15) * 4;    // 0..60
#pragma unroll
    for (int p = 0; p < 4; ++p) {
      const int rr = r + p * 16;     // 0..63
      float4 wv = *(const float4*)(W + (size_t)(g0 + rr) * H + k0 + c);
      float4 hv = *(const float4*)(hprev + (size_t)rr * hstride + k0 + c);
      Ws[c + 0][rr] = wv.x; Ws[c + 1][rr] = wv.y;
      Ws[c + 2][rr] = wv.z; Ws[c + 3][rr] = wv.w;
      Hs[c + 0][rr] = hv.x; Hs[c + 1][rr] = hv.y;
      Hs[c + 2][rr] = hv.z; Hs[c + 3][rr] = hv.w;
    }
  }
  __syncthreads();

  float acc[4][4] = {};
#pragma unroll 16
  for (int kk = 0; kk < 64; ++kk) {
    float4 hb = *(const float4*)&Hs[kk][ty * 4];
    float4 wb = *(const float4*)&Ws[kk][tx * 4];
    float hr[4] = {hb.x, hb.y, hb.z, hb.w};
    float wr[4] = {wb.x, wb.y, wb.z, wb.w};
#pragma unroll
    for (int i = 0; i < 4; ++i)
#pragma unroll
      for (int j = 0; j < 4; ++j) acc[i][j] += hr[i] * wr[j];
  }

#pragma unroll
  for (int i = 0; i < 4; ++i) {
    const int b = ty * 4 + i;
    float4 o = make_float4(acc[i][0], acc[i][1], acc[i][2], acc[i][3]);
    *(float4*)&partial[((size_t)blockIdx.y * B + b) * H + g0 + tx * 4] = o;
  }
}

// ---------------------------------------------------------------------------
// Finalize: y[b,t,g] = tanh(wx(already in y) + sum_ks partial + bias[g]).
// Optionally mirrors into h_last (t == S-1).
// ---------------------------------------------------------------------------
__global__ __launch_bounds__(256) void rnn_finalize(
    const float* __restrict__ partial, const float* __restrict__ bias,
    float* __restrict__ yx, long ystride, float* __restrict__ hlast) {
  const int idx = blockIdx.x * 256 + threadIdx.x;  // 0..65535
  const int b = idx >> 10;
  const int g = idx & 1023;
  float v = yx[(size_t)b * ystride + g] + bias[g];
#pragma unroll
  for (int ks = 0; ks < KSPLIT; ++ks)
    v += partial[((size_t)ks * B + b) * H + g];
  v = tanhf(v);
  yx[(size_t)b * ystride + g] = v;
  if (hlast) hlast[idx] = v;
}

// ---------------------------------------------------------------------------
extern "C" void kernel_launch(void* const* d_in, const int* in_sizes, int n_in,
                              void* d_out, int out_size, void* d_ws, size_t ws_size,
                              hipStream_t stream) {
  const float* x     = (const float*)d_in[0];  // [B,S,I]
  const float* h0    = (const float*)d_in[1];  // [B,H]
  const float* Wih_w = (const float*)d_in[2];  // [H,I]
  const float* Wih_b = (const float*)d_in[3];  // [H]
  const float* Whh_w = (const float*)d_in[4];  // [H,H]
  const float* Whh_b = (const float*)d_in[5];  // [H]

  float* y     = (float*)d_out;                    // [B,S,H]
  float* hlast = y + (size_t)B * S * H;            // [B,H]
  float* partial = (float*)d_ws;                   // KSPLIT*B*H floats = 4 MB

  // Phase 1: wx -> y region. M = B*S = 65536 rows.
  gemm_nt<<<dim3(H / 64, (B * S) / 64), 256, 0, stream>>>(x, Wih_w, Wih_b, y);

  // Phase 2: sequential scan. h_{t-1} lives at y[:, t-1, :].
  for (int t = 0; t < S; ++t) {
    const float* hprev = (t == 0) ? h0 : (y + (size_t)(t - 1) * H);
    const long hstride = (t == 0) ? (long)H : (long)S * H;
    rnn_step_gemm<<<dim3(H / 64, KSPLIT), 256, 0, stream>>>(
        hprev, hstride, Whh_w, partial);
    rnn_finalize<<<256, 256, 0, stream>>>(
        partial, Whh_b, y + (size_t)t * H, (long)S * H,
        (t == S - 1) ? hlast : nullptr);
  }
}